// Round 5
// baseline (1051.152 us; speedup 1.0000x reference)
//
#include <hip/hip_runtime.h>
#include <hip/hip_bf16.h>

typedef __attribute__((ext_vector_type(8))) short short8;
typedef __attribute__((ext_vector_type(4))) float f32x4;

#define SEQ_MASK 32767

__device__ __forceinline__ float b2f_u(unsigned short u){
  union { unsigned int i; float f; } v; v.i = ((unsigned int)u) << 16; return v.f;
}
__device__ __forceinline__ float lo_f(unsigned int u){
  union { unsigned int i; float f; } v; v.i = u << 16; return v.f;
}
__device__ __forceinline__ float hi_f(unsigned int u){
  union { unsigned int i; float f; } v; v.i = u & 0xffff0000u; return v.f;
}
__device__ __forceinline__ unsigned short f2b_u(float f){
  union { __hip_bfloat16 h; unsigned short u; } cv;
  cv.h = __float2bfloat16(f);
  return cv.u;
}
// NaN-suppressing clamp (fmaxf/fminf return the non-NaN operand)
__device__ __forceinline__ float nclamp(float v, float c){
  return fminf(fmaxf(v, -c), c);
}
// dtype-adaptive scalar input read
__device__ __forceinline__ float in_f(const void* p, size_t idx, int isf32){
  return isf32 ? ((const float*)p)[idx] : b2f_u(((const unsigned short*)p)[idx]);
}
// pack two f32 (as bits) into two RN bf16 in one uint
__device__ __forceinline__ unsigned int pk2(unsigned int fa, unsigned int fb){
  union { unsigned int i; float f; } a, b; a.i = fa; b.i = fb;
  return ((unsigned int)f2b_u(a.f)) | (((unsigned int)f2b_u(b.f)) << 16);
}

// ---------------- dtype detector: f32 arrays read as bf16 pairs have garbage
// exponents at even slots; real bf16 data never exceeds ~6 in this problem ----
__global__ __launch_bounds__(256) void detect_k(const void* __restrict__ x,
                                                const void* __restrict__ w,
                                                int* __restrict__ flag)
{
  __shared__ int s;
  if (threadIdx.x == 0) s = 0;
  __syncthreads();
  const unsigned short* xs = (const unsigned short*)x;
  const unsigned short* ws = (const unsigned short*)w;
  int bad = 0;
  for (int i = threadIdx.x; i < 8192; i += 256) {
    float vx = fabsf(b2f_u(xs[2 * i]));
    float vw = fabsf(b2f_u(ws[2 * i]));
    if (!(vx < 1e8f) || !(vw < 1e8f)) bad = 1;   // catches huge + NaN
  }
  if (bad) s = 1;
  __syncthreads();
  if (threadIdx.x == 0) *flag = s;
}

// ---------------- transpose: src[R][C] -> dst[C][R] (bf16 out) ----------------
__global__ __launch_bounds__(256) void transpose_k(const void* __restrict__ src,
                                                   unsigned short* __restrict__ dst,
                                                   int R, int Cc,
                                                   const int* __restrict__ flag)
{
  __shared__ __align__(16) unsigned short t[32][33];
  int isf32 = *flag;
  int tr = blockIdx.y * 32, tc = blockIdx.x * 32;
  int tid = threadIdx.x;
  for (int i = tid; i < 1024; i += 256) {
    int r = i >> 5, c = i & 31;
    float v = nclamp(in_f(src, (size_t)(tr + r) * Cc + tc + c, isf32), 512.f);
    t[r][c] = f2b_u(v);
  }
  __syncthreads();
  for (int i = tid; i < 1024; i += 256) {
    int c = i >> 5, r = i & 31;
    dst[(size_t)(tc + c) * R + tr + r] = t[r][c];
  }
}

// ---------------- bf16 MFMA GEMM ----------------
// C[crow(m), n] = clamp( sum_k A[arow(m), k] * Bt[n][k] + bias[n], +-clampv )
// A / bias dtype-adaptive when (a_ext / b_ext) and *flag; Bt always bf16.
// C is bf16 unless c_f32.
__global__ __launch_bounds__(256) void gemm_bf16(const void* __restrict__ A, int lda,
                                                 int arow_base, int arow_mask, int a_ext,
                                                 const unsigned short* __restrict__ Bt,
                                                 const void* __restrict__ bias, int b_ext,
                                                 void* __restrict__ C, int ldc, int c_f32,
                                                 int crow_base, int crow_mask,
                                                 int K, float clampv,
                                                 const int* __restrict__ flag)
{
  __shared__ __align__(16) unsigned short As[128 * 40];
  __shared__ __align__(16) unsigned short Bs[128 * 40];
  int isf32 = *flag;
  int a32 = a_ext & isf32;
  int b32 = b_ext & isf32;
  int tid = threadIdx.x;
  int bm = blockIdx.y, bn = blockIdx.x;
  int wave = tid >> 6, lane = tid & 63;
  int wm = (wave >> 1) * 64, wn = (wave & 1) * 64;
  int lrow = lane & 15, lq = lane >> 4;

  f32x4 acc[4][4];
  #pragma unroll
  for (int i = 0; i < 4; i++)
    #pragma unroll
    for (int j = 0; j < 4; j++) acc[i][j] = (f32x4){0.f, 0.f, 0.f, 0.f};

  int srow = tid >> 1;
  int shalf = tid & 1;
  int a_row = (arow_base + bm * 128 + srow) & arow_mask;
  const size_t a_base = (size_t)a_row * lda + shalf * 16;
  const size_t b_base = (size_t)(bn * 128 + srow) * K + shalf * 16;
  unsigned short* as_dst = &As[srow * 40 + shalf * 16];
  unsigned short* bs_dst = &Bs[srow * 40 + shalf * 16];

  for (int k0 = 0; k0 < K; k0 += 32) {
    uint4 a0, a1;
    if (a32) {
      const float* ap = (const float*)A + a_base + k0;
      uint4 f0 = *(const uint4*)ap;
      uint4 f1 = *(const uint4*)(ap + 4);
      uint4 f2 = *(const uint4*)(ap + 8);
      uint4 f3 = *(const uint4*)(ap + 12);
      a0.x = pk2(f0.x, f0.y); a0.y = pk2(f0.z, f0.w);
      a0.z = pk2(f1.x, f1.y); a0.w = pk2(f1.z, f1.w);
      a1.x = pk2(f2.x, f2.y); a1.y = pk2(f2.z, f2.w);
      a1.z = pk2(f3.x, f3.y); a1.w = pk2(f3.z, f3.w);
    } else {
      const unsigned short* ap = (const unsigned short*)A + a_base + k0;
      a0 = *(const uint4*)ap;
      a1 = *(const uint4*)(ap + 8);
    }
    uint4 b0 = *(const uint4*)(Bt + b_base + k0);
    uint4 b1 = *(const uint4*)(Bt + b_base + k0 + 8);
    __syncthreads();   // previous iteration's LDS reads complete
    *(uint4*)(as_dst) = a0;
    *(uint4*)(as_dst + 8) = a1;
    *(uint4*)(bs_dst) = b0;
    *(uint4*)(bs_dst + 8) = b1;
    __syncthreads();
    short8 af[4], bfr[4];
    #pragma unroll
    for (int t = 0; t < 4; t++) {
      af[t]  = *(const short8*)&As[(wm + t * 16 + lrow) * 40 + lq * 8];
      bfr[t] = *(const short8*)&Bs[(wn + t * 16 + lrow) * 40 + lq * 8];
    }
    #pragma unroll
    for (int i = 0; i < 4; i++)
      #pragma unroll
      for (int j = 0; j < 4; j++)
        acc[i][j] = __builtin_amdgcn_mfma_f32_16x16x32_bf16(af[i], bfr[j], acc[i][j], 0, 0, 0);
  }

  #pragma unroll
  for (int i = 0; i < 4; i++) {
    int row_l = bm * 128 + wm + i * 16 + lq * 4;
    #pragma unroll
    for (int j = 0; j < 4; j++) {
      int col = bn * 128 + wn + j * 16 + lrow;
      float bv = in_f(bias, col, b32);
      #pragma unroll
      for (int r = 0; r < 4; r++) {
        int grow = (crow_base + row_l + r) & crow_mask;
        float v = nclamp(acc[i][j][r] + bv, clampv);
        if (c_f32) ((float*)C)[(size_t)grow * ldc + col] = v;
        else ((unsigned short*)C)[(size_t)grow * ldc + col] = f2b_u(v);
      }
    }
  }
}

// ---------------- RoPE + RMS, in place on q,k of qkv (local rows) ----------------
__global__ __launch_bounds__(256) void rope_rms_k(unsigned short* __restrict__ qkv,
                                                  const int* __restrict__ coords,
                                                  const void* __restrict__ gq,
                                                  const void* __restrict__ gk,
                                                  int tok_base,
                                                  const int* __restrict__ flag)
{
  int isf32 = *flag;
  int wid = blockIdx.x * 4 + (threadIdx.x >> 6);
  int lane = threadIdx.x & 63;
  int n = wid >> 3, h = wid & 7;
  int gtok = (tok_base + n) & SEQ_MASK;

  int p = lane >> 1;
  float cs = 1.f, sn = 0.f;
  if (p < 30) {
    int ci = p / 10, f = p - ci * 10;
    float freq = exp2f(-1.3287712379549449f * (float)f);  // 10000^(-f/10)
    float th = (float)coords[gtok * 3 + ci] * freq;
    sn = sinf(th);
    cs = cosf(th);
  }

  unsigned short* base = qkv + (size_t)n * 1536 + h * 64;

  // ---- q ----
  {
    float v = b2f_u(base[lane]);
    float partner = __shfl_xor(v, 1, 64);
    float r = (lane & 1) ? (partner * sn + v * cs) : (v * cs - partner * sn);
    float sq = r * r;
    #pragma unroll
    for (int o = 32; o > 0; o >>= 1) sq += __shfl_xor(sq, o, 64);
    float sc = rsqrtf(sq + 1e-12f) * 8.0f;
    base[lane] = f2b_u(nclamp(r * sc * in_f(gq, h * 64 + lane, isf32), 2e4f));
  }
  // ---- k ----
  {
    float v = b2f_u(base[512 + lane]);
    float partner = __shfl_xor(v, 1, 64);
    float r = (lane & 1) ? (partner * sn + v * cs) : (v * cs - partner * sn);
    float sq = r * r;
    #pragma unroll
    for (int o = 32; o > 0; o >>= 1) sq += __shfl_xor(sq, o, 64);
    float sc = rsqrtf(sq + 1e-12f) * 8.0f;
    base[512 + lane] = f2b_u(nclamp(r * sc * in_f(gk, h * 64 + lane, isf32), 2e4f));
  }
}

// ---------------- attention on local rows; h overwrites the q-slot ----------------
__global__ __launch_bounds__(256) void attn_k(unsigned short* qkv)
{
  __shared__ __align__(16) unsigned short Ks[256 * 64];
  __shared__ __align__(16) unsigned short Vs[256 * 64];
  int w = blockIdx.x >> 3, h = blockIdx.x & 7;
  int tid = threadIdx.x;
  int r = w * 256 + tid;

  const unsigned short* krow = qkv + (size_t)r * 1536 + 512 + h * 64;
  const unsigned short* vrow = qkv + (size_t)r * 1536 + 1024 + h * 64;
  #pragma unroll
  for (int s2 = 0; s2 < 8; s2++) {
    ((uint4*)(Ks + tid * 64))[s2] = ((const uint4*)krow)[s2];
    ((uint4*)(Vs + tid * 64))[s2] = ((const uint4*)vrow)[s2];
  }

  float q[64];
  unsigned short* qrow = qkv + (size_t)r * 1536 + h * 64;
  #pragma unroll
  for (int c = 0; c < 8; c++) {
    uint4 u = ((const uint4*)qrow)[c];
    q[c*8+0] = lo_f(u.x); q[c*8+1] = hi_f(u.x);
    q[c*8+2] = lo_f(u.y); q[c*8+3] = hi_f(u.y);
    q[c*8+4] = lo_f(u.z); q[c*8+5] = hi_f(u.z);
    q[c*8+6] = lo_f(u.w); q[c*8+7] = hi_f(u.w);
  }
  __syncthreads();

  float m = -1e30f, l = 0.f;
  for (int j = 0; j < 256; j++) {
    const uint4* kp = (const uint4*)(Ks + j * 64);
    float s = 0.f;
    #pragma unroll
    for (int c = 0; c < 8; c++) {
      uint4 u = kp[c];
      s = fmaf(q[c*8+0], lo_f(u.x), s); s = fmaf(q[c*8+1], hi_f(u.x), s);
      s = fmaf(q[c*8+2], lo_f(u.y), s); s = fmaf(q[c*8+3], hi_f(u.y), s);
      s = fmaf(q[c*8+4], lo_f(u.z), s); s = fmaf(q[c*8+5], hi_f(u.z), s);
      s = fmaf(q[c*8+6], lo_f(u.w), s); s = fmaf(q[c*8+7], hi_f(u.w), s);
    }
    s *= 0.125f;
    float mn = fmaxf(m, s);
    l = l * __expf(m - mn) + __expf(s - mn);
    m = mn;
  }
  float inv_l = 1.f / l;

  float acc[64];
  #pragma unroll
  for (int d = 0; d < 64; d++) acc[d] = 0.f;
  for (int j = 0; j < 256; j++) {
    const uint4* kp = (const uint4*)(Ks + j * 64);
    float s = 0.f;
    #pragma unroll
    for (int c = 0; c < 8; c++) {
      uint4 u = kp[c];
      s = fmaf(q[c*8+0], lo_f(u.x), s); s = fmaf(q[c*8+1], hi_f(u.x), s);
      s = fmaf(q[c*8+2], lo_f(u.y), s); s = fmaf(q[c*8+3], hi_f(u.y), s);
      s = fmaf(q[c*8+4], lo_f(u.z), s); s = fmaf(q[c*8+5], hi_f(u.z), s);
      s = fmaf(q[c*8+6], lo_f(u.w), s); s = fmaf(q[c*8+7], hi_f(u.w), s);
    }
    float pj = __expf(s * 0.125f - m) * inv_l;
    const uint4* vp = (const uint4*)(Vs + j * 64);
    #pragma unroll
    for (int c = 0; c < 8; c++) {
      uint4 u = vp[c];
      acc[c*8+0] = fmaf(pj, lo_f(u.x), acc[c*8+0]);
      acc[c*8+1] = fmaf(pj, hi_f(u.x), acc[c*8+1]);
      acc[c*8+2] = fmaf(pj, lo_f(u.y), acc[c*8+2]);
      acc[c*8+3] = fmaf(pj, hi_f(u.y), acc[c*8+3]);
      acc[c*8+4] = fmaf(pj, lo_f(u.z), acc[c*8+4]);
      acc[c*8+5] = fmaf(pj, hi_f(u.z), acc[c*8+5]);
      acc[c*8+6] = fmaf(pj, lo_f(u.w), acc[c*8+6]);
      acc[c*8+7] = fmaf(pj, hi_f(u.w), acc[c*8+7]);
    }
  }

  unsigned int* hrow = (unsigned int*)qrow;
  #pragma unroll
  for (int d = 0; d < 32; d++) {
    unsigned int lo = f2b_u(nclamp(acc[2 * d],     4e4f));
    unsigned int hi = f2b_u(nclamp(acc[2 * d + 1], 4e4f));
    hrow[d] = (hi << 16) | lo;
  }
}

extern "C" void kernel_launch(void* const* d_in, const int* in_sizes, int n_in,
                              void* d_out, int out_size, void* d_ws, size_t ws_size,
                              hipStream_t stream)
{
  const void* x      = d_in[0];
  const int*  coords = (const int*)d_in[1];
  const void* Wqkv   = d_in[2];
  const void* bqkv   = d_in[3];
  const void* gq     = d_in[4];
  const void* gk     = d_in[5];
  const void* Wout   = d_in[6];
  const void* bout   = d_in[7];

  char* ws = (char*)d_ws;
  int* flag = (int*)ws;                                          // [0, 1024)
  unsigned short* Wt   = (unsigned short*)(ws + 1024);           // 1,572,864 B
  unsigned short* Wot  = (unsigned short*)(ws + 1024 + 1572864); //   524,288 B
  unsigned short* qkvb = (unsigned short*)(ws + 1024 + 2097152); // chunk slab

  // smallest chunk count whose qkv slab fits ws_size (ws_size constant across
  // calls -> identical launch sequence; graph-safe). floor ~2.75 MiB.
  const size_t fixed = 1024 + 2097152;
  int nc = 128;
  for (int c = 1; c <= 128; c <<= 1) {
    size_t need = fixed + (size_t)(32768 / c) * 1536 * 2;
    if (ws_size >= need) { nc = c; break; }
  }
  const int chunk = 32768 / nc;

  detect_k<<<1, 256, 0, stream>>>(x, Wqkv, flag);

  transpose_k<<<dim3(1536 / 32, 512 / 32), 256, 0, stream>>>(Wqkv, Wt, 512, 1536, flag);
  transpose_k<<<dim3(512 / 32, 512 / 32), 256, 0, stream>>>(Wout, Wot, 512, 512, flag);

  for (int c = 0; c < nc; c++) {
    int tok_base = c * chunk + 128;   // +128 = roll(-SHIFT); wrap via & SEQ_MASK

    // qkv_local(bf16) = x[rolled rows](f32) @ Wqkv + b_qkv
    gemm_bf16<<<dim3(12, chunk / 128), 256, 0, stream>>>(
        x, 512, tok_base, SEQ_MASK, 1, Wt, bqkv, 1, qkvb, 1536, 0,
        0, 0x7fffffff, 512, 1e4f, flag);

    rope_rms_k<<<chunk * 2, 256, 0, stream>>>(qkvb, coords, gq, gk, tok_base, flag);

    attn_k<<<(chunk / 256) * 8, 256, 0, stream>>>(qkvb);

    // out(f32) = h(bf16, q-slot) @ Wout + b_out
    gemm_bf16<<<dim3(4, chunk / 128), 256, 0, stream>>>(
        qkvb, 1536, 0, 0x7fffffff, 0, Wot, bout, 1, d_out, 512, 1,
        tok_base, SEQ_MASK, 512, 8e4f, flag);
  }
}

// Round 7
// 475.526 us; speedup vs baseline: 2.2105x; 2.2105x over previous
//
#include <hip/hip_runtime.h>
#include <hip/hip_bf16.h>

typedef __attribute__((ext_vector_type(8))) short short8;
typedef __attribute__((ext_vector_type(4))) float f32x4;

#define SEQ_MASK 32767

__device__ __forceinline__ float b2f_u(unsigned short u){
  union { unsigned int i; float f; } v; v.i = ((unsigned int)u) << 16; return v.f;
}
__device__ __forceinline__ unsigned short f2b_u(float f){
  union { __hip_bfloat16 h; unsigned short u; } cv;
  cv.h = __float2bfloat16(f);
  return cv.u;
}
// NaN-suppressing clamp (fmaxf/fminf return the non-NaN operand)
__device__ __forceinline__ float nclamp(float v, float c){
  return fminf(fmaxf(v, -c), c);
}
// dtype-adaptive scalar input read
__device__ __forceinline__ float in_f(const void* p, size_t idx, int isf32){
  return isf32 ? ((const float*)p)[idx] : b2f_u(((const unsigned short*)p)[idx]);
}
// pack two f32 (as bits) into two RN bf16 in one uint
__device__ __forceinline__ unsigned int pk2(unsigned int fa, unsigned int fb){
  union { unsigned int i; float f; } a, b; a.i = fa; b.i = fb;
  return ((unsigned int)f2b_u(a.f)) | (((unsigned int)f2b_u(b.f)) << 16);
}

// ---------------- dtype detector ----------------
__global__ __launch_bounds__(256) void detect_k(const void* __restrict__ x,
                                                const void* __restrict__ w,
                                                int* __restrict__ flag)
{
  __shared__ int s;
  if (threadIdx.x == 0) s = 0;
  __syncthreads();
  const unsigned short* xs = (const unsigned short*)x;
  const unsigned short* ws = (const unsigned short*)w;
  int bad = 0;
  for (int i = threadIdx.x; i < 8192; i += 256) {
    float vx = fabsf(b2f_u(xs[2 * i]));
    float vw = fabsf(b2f_u(ws[2 * i]));
    if (!(vx < 1e8f) || !(vw < 1e8f)) bad = 1;
  }
  if (bad) s = 1;
  __syncthreads();
  if (threadIdx.x == 0) *flag = s;
}

// ---------------- transpose: src[R][C] -> dst[C][R] (bf16 out) ----------------
__global__ __launch_bounds__(256) void transpose_k(const void* __restrict__ src,
                                                   unsigned short* __restrict__ dst,
                                                   int R, int Cc,
                                                   const int* __restrict__ flag)
{
  __shared__ __align__(16) unsigned short t[32][33];
  int isf32 = *flag;
  int tr = blockIdx.y * 32, tc = blockIdx.x * 32;
  int tid = threadIdx.x;
  for (int i = tid; i < 1024; i += 256) {
    int r = i >> 5, c = i & 31;
    float v = nclamp(in_f(src, (size_t)(tr + r) * Cc + tc + c, isf32), 512.f);
    t[r][c] = f2b_u(v);
  }
  __syncthreads();
  for (int i = tid; i < 1024; i += 256) {
    int c = i >> 5, r = i & 31;
    dst[(size_t)(tc + c) * R + tr + r] = t[r][c];
  }
}

// ---------------- bf16 MFMA GEMM ----------------
__global__ __launch_bounds__(256) void gemm_bf16(const void* __restrict__ A, int lda,
                                                 int arow_base, int arow_mask, int a_ext,
                                                 const unsigned short* __restrict__ Bt,
                                                 const void* __restrict__ bias, int b_ext,
                                                 void* __restrict__ C, int ldc, int c_f32,
                                                 int crow_base, int crow_mask,
                                                 int K, float clampv,
                                                 const int* __restrict__ flag)
{
  __shared__ __align__(16) unsigned short As[128 * 40];
  __shared__ __align__(16) unsigned short Bs[128 * 40];
  int isf32 = *flag;
  int a32 = a_ext & isf32;
  int b32 = b_ext & isf32;
  int tid = threadIdx.x;
  int bm = blockIdx.y, bn = blockIdx.x;
  int wave = tid >> 6, lane = tid & 63;
  int wm = (wave >> 1) * 64, wn = (wave & 1) * 64;
  int lrow = lane & 15, lq = lane >> 4;

  f32x4 acc[4][4];
  #pragma unroll
  for (int i = 0; i < 4; i++)
    #pragma unroll
    for (int j = 0; j < 4; j++) acc[i][j] = (f32x4){0.f, 0.f, 0.f, 0.f};

  int srow = tid >> 1;
  int shalf = tid & 1;
  int a_row = (arow_base + bm * 128 + srow) & arow_mask;
  const size_t a_base = (size_t)a_row * lda + shalf * 16;
  const size_t b_base = (size_t)(bn * 128 + srow) * K + shalf * 16;
  unsigned short* as_dst = &As[srow * 40 + shalf * 16];
  unsigned short* bs_dst = &Bs[srow * 40 + shalf * 16];

  for (int k0 = 0; k0 < K; k0 += 32) {
    uint4 a0, a1;
    if (a32) {
      const float* ap = (const float*)A + a_base + k0;
      uint4 f0 = *(const uint4*)ap;
      uint4 f1 = *(const uint4*)(ap + 4);
      uint4 f2 = *(const uint4*)(ap + 8);
      uint4 f3 = *(const uint4*)(ap + 12);
      a0.x = pk2(f0.x, f0.y); a0.y = pk2(f0.z, f0.w);
      a0.z = pk2(f1.x, f1.y); a0.w = pk2(f1.z, f1.w);
      a1.x = pk2(f2.x, f2.y); a1.y = pk2(f2.z, f2.w);
      a1.z = pk2(f3.x, f3.y); a1.w = pk2(f3.z, f3.w);
    } else {
      const unsigned short* ap = (const unsigned short*)A + a_base + k0;
      a0 = *(const uint4*)ap;
      a1 = *(const uint4*)(ap + 8);
    }
    uint4 b0 = *(const uint4*)(Bt + b_base + k0);
    uint4 b1 = *(const uint4*)(Bt + b_base + k0 + 8);
    __syncthreads();
    *(uint4*)(as_dst) = a0;
    *(uint4*)(as_dst + 8) = a1;
    *(uint4*)(bs_dst) = b0;
    *(uint4*)(bs_dst + 8) = b1;
    __syncthreads();
    short8 af[4], bfr[4];
    #pragma unroll
    for (int t = 0; t < 4; t++) {
      af[t]  = *(const short8*)&As[(wm + t * 16 + lrow) * 40 + lq * 8];
      bfr[t] = *(const short8*)&Bs[(wn + t * 16 + lrow) * 40 + lq * 8];
    }
    #pragma unroll
    for (int i = 0; i < 4; i++)
      #pragma unroll
      for (int j = 0; j < 4; j++)
        acc[i][j] = __builtin_amdgcn_mfma_f32_16x16x32_bf16(af[i], bfr[j], acc[i][j], 0, 0, 0);
  }

  #pragma unroll
  for (int i = 0; i < 4; i++) {
    int row_l = bm * 128 + wm + i * 16 + lq * 4;
    #pragma unroll
    for (int j = 0; j < 4; j++) {
      int col = bn * 128 + wn + j * 16 + lrow;
      float bv = in_f(bias, col, b32);
      #pragma unroll
      for (int r = 0; r < 4; r++) {
        int grow = (crow_base + row_l + r) & crow_mask;
        float v = nclamp(acc[i][j][r] + bv, clampv);
        if (c_f32) ((float*)C)[(size_t)grow * ldc + col] = v;
        else ((unsigned short*)C)[(size_t)grow * ldc + col] = f2b_u(v);
      }
    }
  }
}

// ---------------- RoPE + RMS, in place on q,k of qkv (local rows) ----------------
__global__ __launch_bounds__(256) void rope_rms_k(unsigned short* __restrict__ qkv,
                                                  const int* __restrict__ coords,
                                                  const void* __restrict__ gq,
                                                  const void* __restrict__ gk,
                                                  int tok_base,
                                                  const int* __restrict__ flag)
{
  int isf32 = *flag;
  int wid = blockIdx.x * 4 + (threadIdx.x >> 6);
  int lane = threadIdx.x & 63;
  int n = wid >> 3, h = wid & 7;
  int gtok = (tok_base + n) & SEQ_MASK;

  int p = lane >> 1;
  float cs = 1.f, sn = 0.f;
  if (p < 30) {
    int ci = p / 10, f = p - ci * 10;
    float freq = exp2f(-1.3287712379549449f * (float)f);  // 10000^(-f/10)
    float th = (float)coords[gtok * 3 + ci] * freq;
    sn = sinf(th);
    cs = cosf(th);
  }

  unsigned short* base = qkv + (size_t)n * 1536 + h * 64;

  {
    float v = b2f_u(base[lane]);
    float partner = __shfl_xor(v, 1, 64);
    float r = (lane & 1) ? (partner * sn + v * cs) : (v * cs - partner * sn);
    float sq = r * r;
    #pragma unroll
    for (int o = 32; o > 0; o >>= 1) sq += __shfl_xor(sq, o, 64);
    float sc = rsqrtf(sq + 1e-12f) * 8.0f;
    base[lane] = f2b_u(nclamp(r * sc * in_f(gq, h * 64 + lane, isf32), 2e4f));
  }
  {
    float v = b2f_u(base[512 + lane]);
    float partner = __shfl_xor(v, 1, 64);
    float r = (lane & 1) ? (partner * sn + v * cs) : (v * cs - partner * sn);
    float sq = r * r;
    #pragma unroll
    for (int o = 32; o > 0; o >>= 1) sq += __shfl_xor(sq, o, 64);
    float sc = rsqrtf(sq + 1e-12f) * 8.0f;
    base[512 + lane] = f2b_u(nclamp(r * sc * in_f(gk, h * 64 + lane, isf32), 2e4f));
  }
}

// ---------------- MFMA flash attention; h overwrites the q-slot ----------------
// one block per (local window w, head h); 4 waves, each owns 64 q rows.
// K staged in LDS rows; V staged transposed (Vt[d][key]); P converts
// C-layout -> A-layout via per-wave LDS round-trip (m120 pattern).
__global__ __launch_bounds__(256, 2) void attn_mfma_k(unsigned short* qkv)
{
  constexpr int LDK = 68;   // padded row stride (bf16 elems)
  __shared__ __align__(16) unsigned short Ks[64 * LDK];
  __shared__ __align__(16) unsigned short Vt[64 * LDK];
  __shared__ __align__(16) unsigned short Pb[4][64 * LDK];

  const int w = blockIdx.x >> 3, h = blockIdx.x & 7;
  const int tid = threadIdx.x;
  const int wave = tid >> 6, lane = tid & 63;
  const int l15 = lane & 15, l4 = lane >> 4;
  const int wm = wave * 64;
  const size_t qbase = (size_t)(w * 256) * 1536 + h * 64;   // q-slot base

  // Q fragments (A-layout): row wm+mt*16+l15, d = ks*32+l4*8
  short8 qf[4][2];
  #pragma unroll
  for (int mt = 0; mt < 4; mt++) {
    const unsigned short* qp = qkv + qbase + (size_t)(wm + mt * 16 + l15) * 1536;
    #pragma unroll
    for (int ks = 0; ks < 2; ks++)
      qf[mt][ks] = *(const short8*)(qp + ks * 32 + l4 * 8);
  }

  f32x4 O[4][4];
  float mrow[4][4], lrow[4][4];
  #pragma unroll
  for (int mt = 0; mt < 4; mt++)
    #pragma unroll
    for (int j = 0; j < 4; j++) {
      O[mt][j] = (f32x4){0.f, 0.f, 0.f, 0.f};
      mrow[mt][j] = -1e30f;
      lrow[mt][j] = 0.f;
    }

  const float KC = 0.18033688f;   // SCALE * log2(e)
  const int krow = tid >> 2, c16 = (tid & 3) * 16;

  for (int kt = 0; kt < 4; kt++) {
    if (kt) __syncthreads();   // all waves done reading Ks/Vt of prev tile
    // ---- stage K tile (rows) and V tile (transposed) ----
    {
      const size_t rbase = (size_t)(w * 256 + kt * 64 + krow) * 1536 + h * 64;
      const unsigned short* kg = qkv + rbase + 512 + c16;
      uint4 k0 = *(const uint4*)kg;
      uint4 k1 = *(const uint4*)(kg + 8);
      *(uint4*)&Ks[krow * LDK + c16] = k0;
      *(uint4*)&Ks[krow * LDK + c16 + 8] = k1;
      union { uint4 u[2]; unsigned short s[16]; } vv;
      const unsigned short* vg = qkv + rbase + 1024 + c16;
      vv.u[0] = *(const uint4*)vg;
      vv.u[1] = *(const uint4*)(vg + 8);
      #pragma unroll
      for (int s = 0; s < 16; s++)
        Vt[(c16 + s) * LDK + krow] = vv.s[s];
    }
    __syncthreads();

    // ---- S = Q @ K^T (C-layout: row=l4*4+r, col=l15) ----
    f32x4 S[4][4];
    #pragma unroll
    for (int mt = 0; mt < 4; mt++)
      #pragma unroll
      for (int nt = 0; nt < 4; nt++) S[mt][nt] = (f32x4){0.f, 0.f, 0.f, 0.f};
    #pragma unroll
    for (int ks = 0; ks < 2; ks++) {
      #pragma unroll
      for (int nt = 0; nt < 4; nt++) {
        short8 kf = *(const short8*)&Ks[(nt * 16 + l15) * LDK + ks * 32 + l4 * 8];
        #pragma unroll
        for (int mt = 0; mt < 4; mt++)
          S[mt][nt] = __builtin_amdgcn_mfma_f32_16x16x32_bf16(qf[mt][ks], kf, S[mt][nt], 0, 0, 0);
      }
    }

    // ---- online softmax (per row; 16 lanes of a row-group agree) ----
    #pragma unroll
    for (int mt = 0; mt < 4; mt++) {
      #pragma unroll
      for (int r = 0; r < 4; r++) {
        float mx = fmaxf(fmaxf(S[mt][0][r], S[mt][1][r]),
                         fmaxf(S[mt][2][r], S[mt][3][r]));
        mx = fmaxf(mx, __shfl_xor(mx, 1, 64));
        mx = fmaxf(mx, __shfl_xor(mx, 2, 64));
        mx = fmaxf(mx, __shfl_xor(mx, 4, 64));
        mx = fmaxf(mx, __shfl_xor(mx, 8, 64));
        float mnew = fmaxf(mrow[mt][r], mx);
        float alpha = exp2f((mrow[mt][r] - mnew) * KC);
        mrow[mt][r] = mnew;
        float ps = 0.f;
        #pragma unroll
        for (int nt = 0; nt < 4; nt++) {
          float p = exp2f((S[mt][nt][r] - mnew) * KC);
          S[mt][nt][r] = p;
          ps += p;
        }
        ps += __shfl_xor(ps, 1, 64);
        ps += __shfl_xor(ps, 2, 64);
        ps += __shfl_xor(ps, 4, 64);
        ps += __shfl_xor(ps, 8, 64);
        lrow[mt][r] = lrow[mt][r] * alpha + ps;
        #pragma unroll
        for (int jd = 0; jd < 4; jd++) O[mt][jd][r] *= alpha;
      }
    }

    // ---- P: C-layout regs -> LDS -> A-layout frags (per-wave buffer) ----
    unsigned short* pb = &Pb[wave][0];
    #pragma unroll
    for (int mt = 0; mt < 4; mt++)
      #pragma unroll
      for (int nt = 0; nt < 4; nt++)
        #pragma unroll
        for (int r = 0; r < 4; r++)
          pb[(mt * 16 + l4 * 4 + r) * LDK + nt * 16 + l15] = f2b_u(S[mt][nt][r]);

    // ---- O += P @ V ----
    #pragma unroll
    for (int ks = 0; ks < 2; ks++) {
      short8 vf[4];
      #pragma unroll
      for (int jd = 0; jd < 4; jd++)
        vf[jd] = *(const short8*)&Vt[(jd * 16 + l15) * LDK + ks * 32 + l4 * 8];
      #pragma unroll
      for (int mt = 0; mt < 4; mt++) {
        short8 pf = *(const short8*)&pb[(mt * 16 + l15) * LDK + ks * 32 + l4 * 8];
        #pragma unroll
        for (int jd = 0; jd < 4; jd++)
          O[mt][jd] = __builtin_amdgcn_mfma_f32_16x16x32_bf16(pf, vf[jd], O[mt][jd], 0, 0, 0);
      }
    }
  }

  // ---- epilogue: normalize, write h into q-slot (C-layout addressing) ----
  #pragma unroll
  for (int mt = 0; mt < 4; mt++)
    #pragma unroll
    for (int r = 0; r < 4; r++) {
      float inv = 1.f / lrow[mt][r];
      unsigned short* op = qkv + qbase + (size_t)(wm + mt * 16 + l4 * 4 + r) * 1536;
      #pragma unroll
      for (int jd = 0; jd < 4; jd++)
        op[jd * 16 + l15] = f2b_u(O[mt][jd][r] * inv);
    }
}

extern "C" void kernel_launch(void* const* d_in, const int* in_sizes, int n_in,
                              void* d_out, int out_size, void* d_ws, size_t ws_size,
                              hipStream_t stream)
{
  const void* x      = d_in[0];
  const int*  coords = (const int*)d_in[1];
  const void* Wqkv   = d_in[2];
  const void* bqkv   = d_in[3];
  const void* gq     = d_in[4];
  const void* gk     = d_in[5];
  const void* Wout   = d_in[6];
  const void* bout   = d_in[7];

  char* ws = (char*)d_ws;
  int* flag = (int*)ws;                                          // [0, 1024)
  unsigned short* Wt   = (unsigned short*)(ws + 1024);           // 1,572,864 B
  unsigned short* Wot  = (unsigned short*)(ws + 1024 + 1572864); //   524,288 B
  unsigned short* qkvb = (unsigned short*)(ws + 1024 + 2097152); // chunk slab

  const size_t fixed = 1024 + 2097152;
  int nc = 128;
  for (int c = 1; c <= 128; c <<= 1) {
    size_t need = fixed + (size_t)(32768 / c) * 1536 * 2;
    if (ws_size >= need) { nc = c; break; }
  }
  const int chunk = 32768 / nc;

  detect_k<<<1, 256, 0, stream>>>(x, Wqkv, flag);

  transpose_k<<<dim3(1536 / 32, 512 / 32), 256, 0, stream>>>(Wqkv, Wt, 512, 1536, flag);
  transpose_k<<<dim3(512 / 32, 512 / 32), 256, 0, stream>>>(Wout, Wot, 512, 512, flag);

  for (int c = 0; c < nc; c++) {
    int tok_base = c * chunk + 128;   // +128 = roll(-SHIFT); wrap via & SEQ_MASK

    // qkv_local(bf16) = x[rolled rows](f32) @ Wqkv + b_qkv
    gemm_bf16<<<dim3(12, chunk / 128), 256, 0, stream>>>(
        x, 512, tok_base, SEQ_MASK, 1, Wt, bqkv, 1, qkvb, 1536, 0,
        0, 0x7fffffff, 512, 1e4f, flag);

    rope_rms_k<<<chunk * 2, 256, 0, stream>>>(qkvb, coords, gq, gk, tok_base, flag);

    attn_mfma_k<<<(chunk / 256) * 8, 256, 0, stream>>>(qkvb);

    // out(f32) = h(bf16, q-slot) @ Wout + b_out
    gemm_bf16<<<dim3(4, chunk / 128), 256, 0, stream>>>(
        qkvb, 1536, 0, 0x7fffffff, 0, Wot, bout, 1, d_out, 512, 1,
        tok_base, SEQ_MASK, 512, 8e4f, flag);
  }
}

// Round 8
// 371.811 us; speedup vs baseline: 2.8271x; 1.2789x over previous
//
#include <hip/hip_runtime.h>
#include <hip/hip_bf16.h>

typedef __attribute__((ext_vector_type(8))) short short8;
typedef __attribute__((ext_vector_type(4))) float f32x4;

#define SEQ_MASK 32767

__device__ __forceinline__ float b2f_u(unsigned short u){
  union { unsigned int i; float f; } v; v.i = ((unsigned int)u) << 16; return v.f;
}
__device__ __forceinline__ unsigned short f2b_u(float f){
  union { __hip_bfloat16 h; unsigned short u; } cv;
  cv.h = __float2bfloat16(f);
  return cv.u;
}
__device__ __forceinline__ float nclamp(float v, float c){
  return fminf(fmaxf(v, -c), c);
}
__device__ __forceinline__ float in_f(const void* p, size_t idx, int isf32){
  return isf32 ? ((const float*)p)[idx] : b2f_u(((const unsigned short*)p)[idx]);
}
__device__ __forceinline__ unsigned int pk2(unsigned int fa, unsigned int fb){
  union { unsigned int i; float f; } a, b; a.i = fa; b.i = fb;
  return ((unsigned int)f2b_u(a.f)) | (((unsigned int)f2b_u(b.f)) << 16);
}
// 16-B async global->LDS DMA (lane-contiguous LDS dest, m97 pattern)
__device__ __forceinline__ void llds16(const unsigned short* g, unsigned short* l){
  __builtin_amdgcn_global_load_lds((const __attribute__((address_space(1))) void*)g,
                                   (__attribute__((address_space(3))) void*)l, 16, 0, 0);
}

// ---------------- dtype detector ----------------
__global__ __launch_bounds__(256) void detect_k(const void* __restrict__ x,
                                                const void* __restrict__ w,
                                                int* __restrict__ flag)
{
  __shared__ int s;
  if (threadIdx.x == 0) s = 0;
  __syncthreads();
  const unsigned short* xs = (const unsigned short*)x;
  const unsigned short* ws = (const unsigned short*)w;
  int bad = 0;
  for (int i = threadIdx.x; i < 8192; i += 256) {
    float vx = fabsf(b2f_u(xs[2 * i]));
    float vw = fabsf(b2f_u(ws[2 * i]));
    if (!(vx < 1e8f) || !(vw < 1e8f)) bad = 1;
  }
  if (bad) s = 1;
  __syncthreads();
  if (threadIdx.x == 0) *flag = s;
}

// ---------------- pack x -> bf16 (or bf16 copy); 8 elems/thread ----------------
__global__ __launch_bounds__(256) void pack_k(const void* __restrict__ x,
                                              unsigned short* __restrict__ xb,
                                              const int* __restrict__ flag)
{
  int isf32 = *flag;
  size_t t = (size_t)blockIdx.x * 256 + threadIdx.x;
  if (isf32) {
    const uint4* xp = (const uint4*)x;
    uint4 a = xp[2 * t], b = xp[2 * t + 1];
    uint4 o;
    o.x = pk2(a.x, a.y); o.y = pk2(a.z, a.w);
    o.z = pk2(b.x, b.y); o.w = pk2(b.z, b.w);
    ((uint4*)xb)[t] = o;
  } else {
    ((uint4*)xb)[t] = ((const uint4*)x)[t];
  }
}

// ---------------- transpose: src[R][C] -> dst[C][R] (bf16 out) ----------------
__global__ __launch_bounds__(256) void transpose_k(const void* __restrict__ src,
                                                   unsigned short* __restrict__ dst,
                                                   int R, int Cc,
                                                   const int* __restrict__ flag)
{
  __shared__ __align__(16) unsigned short t[32][33];
  int isf32 = *flag;
  int tr = blockIdx.y * 32, tc = blockIdx.x * 32;
  int tid = threadIdx.x;
  for (int i = tid; i < 1024; i += 256) {
    int r = i >> 5, c = i & 31;
    t[r][c] = f2b_u(in_f(src, (size_t)(tr + r) * Cc + tc + c, isf32));
  }
  __syncthreads();
  for (int i = tid; i < 1024; i += 256) {
    int c = i >> 5, r = i & 31;
    dst[(size_t)(tc + c) * R + tr + r] = t[r][c];
  }
}

// ---------------- main GEMM: bf16 A via global_load_lds, fused epilogues ----
// mode 1: C=qkv bf16 with fused bias+RoPE+RMS on q/k regions (N=1536)
// mode 2: C=f32 with bias (final projection)
__global__ __launch_bounds__(256) void gemm_k(const unsigned short* __restrict__ A, int lda,
                                              int arow_base, int arow_mask,
                                              const unsigned short* __restrict__ Bt,
                                              const void* __restrict__ bias, int b_ext,
                                              void* __restrict__ C, int ldc, int mode,
                                              int crow_base, int crow_mask, int K,
                                              const int* __restrict__ coords,
                                              const void* __restrict__ gq,
                                              const void* __restrict__ gk,
                                              const int* __restrict__ flag)
{
  __shared__ __align__(16) unsigned short As[128 * 32];
  __shared__ __align__(16) unsigned short Bs[128 * 32];
  int isf32 = *flag;
  int b32 = b_ext & isf32;
  int tid = threadIdx.x;
  int bm = blockIdx.y, bn = blockIdx.x;
  int wave = tid >> 6, lane = tid & 63;
  int wm = (wave >> 1) * 64, wn = (wave & 1) * 64;
  int l15 = lane & 15, lq = lane >> 4;

  f32x4 acc[4][4];
  #pragma unroll
  for (int i = 0; i < 4; i++)
    #pragma unroll
    for (int j = 0; j < 4; j++) acc[i][j] = (f32x4){0.f, 0.f, 0.f, 0.f};

  const int tq = tid >> 2;           // 0..63
  const int tc8 = (tid & 3) * 8;     // col offset (elems)
  int ar0 = (arow_base + bm * 128 + tq) & arow_mask;
  int ar1 = (arow_base + bm * 128 + 64 + tq) & arow_mask;
  const size_t a0 = (size_t)ar0 * lda + tc8;
  const size_t a1 = (size_t)ar1 * lda + tc8;
  const size_t b0 = (size_t)(bn * 128 + tq) * K + tc8;
  const size_t b1 = (size_t)(bn * 128 + 64 + tq) * K + tc8;
  unsigned short* asd = As + tid * 8;
  unsigned short* bsd = Bs + tid * 8;

  for (int k0 = 0; k0 < K; k0 += 32) {
    __syncthreads();                 // prev iteration's LDS reads complete
    llds16(A + a0 + k0, asd);
    llds16(A + a1 + k0, asd + 2048);
    llds16(Bt + b0 + k0, bsd);
    llds16(Bt + b1 + k0, bsd + 2048);
    __syncthreads();                 // drains vmcnt -> DMA visible
    short8 af[4], bf[4];
    #pragma unroll
    for (int t = 0; t < 4; t++) {
      af[t] = *(const short8*)&As[(wm + t * 16 + l15) * 32 + lq * 8];
      bf[t] = *(const short8*)&Bs[(wn + t * 16 + l15) * 32 + lq * 8];
    }
    #pragma unroll
    for (int i = 0; i < 4; i++)
      #pragma unroll
      for (int j = 0; j < 4; j++)
        acc[i][j] = __builtin_amdgcn_mfma_f32_16x16x32_bf16(af[i], bf[j], acc[i][j], 0, 0, 0);
  }

  if (mode == 1) {
    // stage this block's 128 token coords in LDS (reuse As)
    __syncthreads();
    int* cs = (int*)As;
    if (tid < 128) {
      int gt = (arow_base + bm * 128 + tid) & arow_mask;
      cs[tid * 3 + 0] = coords[gt * 3 + 0];
      cs[tid * 3 + 1] = coords[gt * 3 + 1];
      cs[tid * 3 + 2] = coords[gt * 3 + 2];
    }
    __syncthreads();

    int region = bn >> 2;                         // 0=q 1=k 2=v
    const void* gamma = region ? gk : gq;
    int hd = ((bn * 128 + wn) >> 6) & 7;          // head of this wave's col block
    // per-j rope constants (d = j*16+l15, p = d>>1)
    int pj[4], cij[4];
    float fqj[4];
    #pragma unroll
    for (int j = 0; j < 4; j++) {
      int d = j * 16 + l15;
      pj[j] = d >> 1;
      int ci = pj[j] >= 20 ? 2 : (pj[j] >= 10 ? 1 : 0);
      cij[j] = ci;
      fqj[j] = exp2f(-1.3287712379549449f * (float)(pj[j] - ci * 10));
    }
    float gam[4], bv[4];
    #pragma unroll
    for (int j = 0; j < 4; j++) {
      int col = bn * 128 + wn + j * 16 + l15;
      bv[j] = in_f(bias, col, b32);
      if (region < 2) gam[j] = in_f(gamma, hd * 64 + (j * 16 + l15), isf32);
    }

    #pragma unroll
    for (int i = 0; i < 4; i++) {
      #pragma unroll
      for (int r = 0; r < 4; r++) {
        int lr = wm + i * 16 + lq * 4 + r;        // block-local row
        float vv[4];
        #pragma unroll
        for (int j = 0; j < 4; j++) vv[j] = acc[i][j][r] + bv[j];
        if (region < 2) {
          const int* c3 = &cs[lr * 3];
          #pragma unroll
          for (int j = 0; j < 4; j++) {
            float partner = __shfl_xor(vv[j], 1, 64);
            if (pj[j] < 30) {
              float th = (float)c3[cij[j]] * fqj[j];
              float sn, csn;
              __sincosf(th, &sn, &csn);
              vv[j] = (l15 & 1) ? (partner * sn + vv[j] * csn)
                                : (vv[j] * csn - partner * sn);
            }
          }
          float ss = vv[0]*vv[0] + vv[1]*vv[1] + vv[2]*vv[2] + vv[3]*vv[3];
          ss += __shfl_xor(ss, 1, 64);
          ss += __shfl_xor(ss, 2, 64);
          ss += __shfl_xor(ss, 4, 64);
          ss += __shfl_xor(ss, 8, 64);
          float sc = rsqrtf(ss + 1e-12f) * 8.0f;
          #pragma unroll
          for (int j = 0; j < 4; j++) vv[j] = vv[j] * sc * gam[j];
        }
        int grow = bm * 128 + lr;
        unsigned short* cp = (unsigned short*)C + (size_t)grow * ldc + bn * 128 + wn;
        #pragma unroll
        for (int j = 0; j < 4; j++) cp[j * 16 + l15] = f2b_u(vv[j]);
      }
    }
  } else {
    // mode 2: f32 out with bias, rolled row mapping
    #pragma unroll
    for (int i = 0; i < 4; i++) {
      #pragma unroll
      for (int j = 0; j < 4; j++) {
        int col = bn * 128 + wn + j * 16 + l15;
        float bvv = in_f(bias, col, b32);
        #pragma unroll
        for (int r = 0; r < 4; r++) {
          int grow = (crow_base + bm * 128 + wm + i * 16 + lq * 4 + r) & crow_mask;
          ((float*)C)[(size_t)grow * ldc + col] = acc[i][j][r] + bvv;
        }
      }
    }
  }
}

// ---------------- fallback GEMM (f32-A capable, register staging) ----------------
__global__ __launch_bounds__(256) void gemm_bf16(const void* __restrict__ A, int lda,
                                                 int arow_base, int arow_mask, int a_ext,
                                                 const unsigned short* __restrict__ Bt,
                                                 const void* __restrict__ bias, int b_ext,
                                                 void* __restrict__ C, int ldc, int c_f32,
                                                 int crow_base, int crow_mask,
                                                 int K, const int* __restrict__ flag)
{
  __shared__ __align__(16) unsigned short As[128 * 40];
  __shared__ __align__(16) unsigned short Bs[128 * 40];
  int isf32 = *flag;
  int a32 = a_ext & isf32;
  int b32 = b_ext & isf32;
  int tid = threadIdx.x;
  int bm = blockIdx.y, bn = blockIdx.x;
  int wave = tid >> 6, lane = tid & 63;
  int wm = (wave >> 1) * 64, wn = (wave & 1) * 64;
  int lrow = lane & 15, lq = lane >> 4;

  f32x4 acc[4][4];
  #pragma unroll
  for (int i = 0; i < 4; i++)
    #pragma unroll
    for (int j = 0; j < 4; j++) acc[i][j] = (f32x4){0.f, 0.f, 0.f, 0.f};

  int srow = tid >> 1;
  int shalf = tid & 1;
  int a_row = (arow_base + bm * 128 + srow) & arow_mask;
  const size_t a_base = (size_t)a_row * lda + shalf * 16;
  const size_t b_base = (size_t)(bn * 128 + srow) * K + shalf * 16;
  unsigned short* as_dst = &As[srow * 40 + shalf * 16];
  unsigned short* bs_dst = &Bs[srow * 40 + shalf * 16];

  for (int k0 = 0; k0 < K; k0 += 32) {
    uint4 a0, a1;
    if (a32) {
      const float* ap = (const float*)A + a_base + k0;
      uint4 f0 = *(const uint4*)ap;
      uint4 f1 = *(const uint4*)(ap + 4);
      uint4 f2 = *(const uint4*)(ap + 8);
      uint4 f3 = *(const uint4*)(ap + 12);
      a0.x = pk2(f0.x, f0.y); a0.y = pk2(f0.z, f0.w);
      a0.z = pk2(f1.x, f1.y); a0.w = pk2(f1.z, f1.w);
      a1.x = pk2(f2.x, f2.y); a1.y = pk2(f2.z, f2.w);
      a1.z = pk2(f3.x, f3.y); a1.w = pk2(f3.z, f3.w);
    } else {
      const unsigned short* ap = (const unsigned short*)A + a_base + k0;
      a0 = *(const uint4*)ap;
      a1 = *(const uint4*)(ap + 8);
    }
    uint4 bb0 = *(const uint4*)(Bt + b_base + k0);
    uint4 bb1 = *(const uint4*)(Bt + b_base + k0 + 8);
    __syncthreads();
    *(uint4*)(as_dst) = a0;
    *(uint4*)(as_dst + 8) = a1;
    *(uint4*)(bs_dst) = bb0;
    *(uint4*)(bs_dst + 8) = bb1;
    __syncthreads();
    short8 af[4], bfr[4];
    #pragma unroll
    for (int t = 0; t < 4; t++) {
      af[t]  = *(const short8*)&As[(wm + t * 16 + lrow) * 40 + lq * 8];
      bfr[t] = *(const short8*)&Bs[(wn + t * 16 + lrow) * 40 + lq * 8];
    }
    #pragma unroll
    for (int i = 0; i < 4; i++)
      #pragma unroll
      for (int j = 0; j < 4; j++)
        acc[i][j] = __builtin_amdgcn_mfma_f32_16x16x32_bf16(af[i], bfr[j], acc[i][j], 0, 0, 0);
  }

  #pragma unroll
  for (int i = 0; i < 4; i++) {
    int row_l = bm * 128 + wm + i * 16 + lq * 4;
    #pragma unroll
    for (int j = 0; j < 4; j++) {
      int col = bn * 128 + wn + j * 16 + lrow;
      float bvv = in_f(bias, col, b32);
      #pragma unroll
      for (int r = 0; r < 4; r++) {
        int grow = (crow_base + row_l + r) & crow_mask;
        float v = acc[i][j][r] + bvv;
        if (c_f32) ((float*)C)[(size_t)grow * ldc + col] = v;
        else ((unsigned short*)C)[(size_t)grow * ldc + col] = f2b_u(v);
      }
    }
  }
}

// ---------------- fallback RoPE + RMS ----------------
__global__ __launch_bounds__(256) void rope_rms_k(unsigned short* __restrict__ qkv,
                                                  const int* __restrict__ coords,
                                                  const void* __restrict__ gq,
                                                  const void* __restrict__ gk,
                                                  int tok_base,
                                                  const int* __restrict__ flag)
{
  int isf32 = *flag;
  int wid = blockIdx.x * 4 + (threadIdx.x >> 6);
  int lane = threadIdx.x & 63;
  int n = wid >> 3, h = wid & 7;
  int gtok = (tok_base + n) & SEQ_MASK;

  int p = lane >> 1;
  float cs = 1.f, sn = 0.f;
  if (p < 30) {
    int ci = p / 10, f = p - ci * 10;
    float freq = exp2f(-1.3287712379549449f * (float)f);
    float th = (float)coords[gtok * 3 + ci] * freq;
    sn = sinf(th);
    cs = cosf(th);
  }

  unsigned short* base = qkv + (size_t)n * 1536 + h * 64;
  {
    float v = b2f_u(base[lane]);
    float partner = __shfl_xor(v, 1, 64);
    float r = (lane & 1) ? (partner * sn + v * cs) : (v * cs - partner * sn);
    float sq = r * r;
    #pragma unroll
    for (int o = 32; o > 0; o >>= 1) sq += __shfl_xor(sq, o, 64);
    float sc = rsqrtf(sq + 1e-12f) * 8.0f;
    base[lane] = f2b_u(r * sc * in_f(gq, h * 64 + lane, isf32));
  }
  {
    float v = b2f_u(base[512 + lane]);
    float partner = __shfl_xor(v, 1, 64);
    float r = (lane & 1) ? (partner * sn + v * cs) : (v * cs - partner * sn);
    float sq = r * r;
    #pragma unroll
    for (int o = 32; o > 0; o >>= 1) sq += __shfl_xor(sq, o, 64);
    float sc = rsqrtf(sq + 1e-12f) * 8.0f;
    base[512 + lane] = f2b_u(r * sc * in_f(gk, h * 64 + lane, isf32));
  }
}

// ---------------- MFMA flash attention; h overwrites the q-slot ----------------
__global__ __launch_bounds__(256, 2) void attn_mfma_k(unsigned short* qkv)
{
  constexpr int LDK = 68;
  __shared__ __align__(16) unsigned short Ks[64 * LDK];
  __shared__ __align__(16) unsigned short Vt[64 * LDK];
  __shared__ __align__(16) unsigned short Pb[4][64 * LDK];

  const int w = blockIdx.x >> 3, h = blockIdx.x & 7;
  const int tid = threadIdx.x;
  const int wave = tid >> 6, lane = tid & 63;
  const int l15 = lane & 15, l4 = lane >> 4;
  const int wm = wave * 64;
  const size_t qbase = (size_t)(w * 256) * 1536 + h * 64;

  short8 qf[4][2];
  #pragma unroll
  for (int mt = 0; mt < 4; mt++) {
    const unsigned short* qp = qkv + qbase + (size_t)(wm + mt * 16 + l15) * 1536;
    #pragma unroll
    for (int ks = 0; ks < 2; ks++)
      qf[mt][ks] = *(const short8*)(qp + ks * 32 + l4 * 8);
  }

  f32x4 O[4][4];
  float mrow[4][4], lrow[4][4];
  #pragma unroll
  for (int mt = 0; mt < 4; mt++)
    #pragma unroll
    for (int j = 0; j < 4; j++) {
      O[mt][j] = (f32x4){0.f, 0.f, 0.f, 0.f};
      mrow[mt][j] = -1e30f;
      lrow[mt][j] = 0.f;
    }

  const float KC = 0.18033688f;
  const int krow = tid >> 2, c16 = (tid & 3) * 16;

  for (int kt = 0; kt < 4; kt++) {
    if (kt) __syncthreads();
    {
      const size_t rbase = (size_t)(w * 256 + kt * 64 + krow) * 1536 + h * 64;
      const unsigned short* kg = qkv + rbase + 512 + c16;
      uint4 k0 = *(const uint4*)kg;
      uint4 k1 = *(const uint4*)(kg + 8);
      *(uint4*)&Ks[krow * LDK + c16] = k0;
      *(uint4*)&Ks[krow * LDK + c16 + 8] = k1;
      union { uint4 u[2]; unsigned short s[16]; } vv;
      const unsigned short* vg = qkv + rbase + 1024 + c16;
      vv.u[0] = *(const uint4*)vg;
      vv.u[1] = *(const uint4*)(vg + 8);
      #pragma unroll
      for (int s = 0; s < 16; s++)
        Vt[(c16 + s) * LDK + krow] = vv.s[s];
    }
    __syncthreads();

    f32x4 S[4][4];
    #pragma unroll
    for (int mt = 0; mt < 4; mt++)
      #pragma unroll
      for (int nt = 0; nt < 4; nt++) S[mt][nt] = (f32x4){0.f, 0.f, 0.f, 0.f};
    #pragma unroll
    for (int ks = 0; ks < 2; ks++) {
      #pragma unroll
      for (int nt = 0; nt < 4; nt++) {
        short8 kf = *(const short8*)&Ks[(nt * 16 + l15) * LDK + ks * 32 + l4 * 8];
        #pragma unroll
        for (int mt = 0; mt < 4; mt++)
          S[mt][nt] = __builtin_amdgcn_mfma_f32_16x16x32_bf16(qf[mt][ks], kf, S[mt][nt], 0, 0, 0);
      }
    }

    #pragma unroll
    for (int mt = 0; mt < 4; mt++) {
      #pragma unroll
      for (int r = 0; r < 4; r++) {
        float mx = fmaxf(fmaxf(S[mt][0][r], S[mt][1][r]),
                         fmaxf(S[mt][2][r], S[mt][3][r]));
        mx = fmaxf(mx, __shfl_xor(mx, 1, 64));
        mx = fmaxf(mx, __shfl_xor(mx, 2, 64));
        mx = fmaxf(mx, __shfl_xor(mx, 4, 64));
        mx = fmaxf(mx, __shfl_xor(mx, 8, 64));
        float mnew = fmaxf(mrow[mt][r], mx);
        float alpha = exp2f((mrow[mt][r] - mnew) * KC);
        mrow[mt][r] = mnew;
        float ps = 0.f;
        #pragma unroll
        for (int nt = 0; nt < 4; nt++) {
          float p = exp2f((S[mt][nt][r] - mnew) * KC);
          S[mt][nt][r] = p;
          ps += p;
        }
        ps += __shfl_xor(ps, 1, 64);
        ps += __shfl_xor(ps, 2, 64);
        ps += __shfl_xor(ps, 4, 64);
        ps += __shfl_xor(ps, 8, 64);
        lrow[mt][r] = lrow[mt][r] * alpha + ps;
        #pragma unroll
        for (int jd = 0; jd < 4; jd++) O[mt][jd][r] *= alpha;
      }
    }

    unsigned short* pb = &Pb[wave][0];
    #pragma unroll
    for (int mt = 0; mt < 4; mt++)
      #pragma unroll
      for (int nt = 0; nt < 4; nt++)
        #pragma unroll
        for (int r = 0; r < 4; r++)
          pb[(mt * 16 + l4 * 4 + r) * LDK + nt * 16 + l15] = f2b_u(S[mt][nt][r]);

    #pragma unroll
    for (int ks = 0; ks < 2; ks++) {
      short8 vf[4];
      #pragma unroll
      for (int jd = 0; jd < 4; jd++)
        vf[jd] = *(const short8*)&Vt[(jd * 16 + l15) * LDK + ks * 32 + l4 * 8];
      #pragma unroll
      for (int mt = 0; mt < 4; mt++) {
        short8 pf = *(const short8*)&pb[(mt * 16 + l15) * LDK + ks * 32 + l4 * 8];
        #pragma unroll
        for (int jd = 0; jd < 4; jd++)
          O[mt][jd] = __builtin_amdgcn_mfma_f32_16x16x32_bf16(pf, vf[jd], O[mt][jd], 0, 0, 0);
      }
    }
  }

  #pragma unroll
  for (int mt = 0; mt < 4; mt++)
    #pragma unroll
    for (int r = 0; r < 4; r++) {
      float inv = 1.f / lrow[mt][r];
      unsigned short* op = qkv + qbase + (size_t)(wm + mt * 16 + l4 * 4 + r) * 1536;
      #pragma unroll
      for (int jd = 0; jd < 4; jd++)
        op[jd * 16 + l15] = f2b_u(O[mt][jd][r] * inv);
    }
}

extern "C" void kernel_launch(void* const* d_in, const int* in_sizes, int n_in,
                              void* d_out, int out_size, void* d_ws, size_t ws_size,
                              hipStream_t stream)
{
  const void* x      = d_in[0];
  const int*  coords = (const int*)d_in[1];
  const void* Wqkv   = d_in[2];
  const void* bqkv   = d_in[3];
  const void* gq     = d_in[4];
  const void* gk     = d_in[5];
  const void* Wout   = d_in[6];
  const void* bout   = d_in[7];

  char* ws = (char*)d_ws;
  int* flag = (int*)ws;                                          // [0, 1024)
  unsigned short* Wt   = (unsigned short*)(ws + 1024);           // 1,572,864 B
  unsigned short* Wot  = (unsigned short*)(ws + 1024 + 1572864); //   524,288 B
  unsigned short* qkvb = (unsigned short*)(ws + 1024 + 2097152); // qkv slab

  const size_t fixed = 1024 + 2097152;
  const size_t qkvN = (size_t)32768 * 1536 * 2;   // 100,663,296

  detect_k<<<1, 256, 0, stream>>>(x, Wqkv, flag);
  transpose_k<<<dim3(1536 / 32, 512 / 32), 256, 0, stream>>>(Wqkv, Wt, 512, 1536, flag);
  transpose_k<<<dim3(512 / 32, 512 / 32), 256, 0, stream>>>(Wout, Wot, 512, 512, flag);

  if (ws_size >= fixed + qkvN) {
    // -------- fast path: single chunk, DMA-staged GEMMs, fused rope --------
    // x_bf16 scratch: spare ws if it fits, else tail-use d_out (overwritten
    // only by the final gemm, stream-ordered after all reads)
    unsigned short* xb = (ws_size >= fixed + qkvN + 33554432)
                             ? (unsigned short*)(ws + fixed + qkvN)
                             : (unsigned short*)d_out;

    pack_k<<<8192, 256, 0, stream>>>(x, xb, flag);

    // qkv = rope_rms(x_roll @ Wqkv + b)  [fused epilogue]
    gemm_k<<<dim3(12, 256), 256, 0, stream>>>(
        xb, 512, 128, SEQ_MASK, Wt, bqkv, 1, qkvb, 1536, 1,
        0, 0x7fffffff, 512, coords, gq, gk, flag);

    attn_mfma_k<<<1024, 256, 0, stream>>>(qkvb);

    // out(f32, unrolled rows) = h @ Wout + b_out
    gemm_k<<<dim3(4, 256), 256, 0, stream>>>(
        qkvb, 1536, 0, 0x7fffffff, Wot, bout, 1, d_out, 512, 2,
        128, SEQ_MASK, 512, coords, gq, gk, flag);
  } else {
    // -------- fallback: chunked pipeline (small workspace) --------
    int nc = 128;
    for (int c = 2; c <= 128; c <<= 1) {
      size_t need = fixed + (size_t)(32768 / c) * 1536 * 2;
      if (ws_size >= need) { nc = c; break; }
    }
    const int chunk = 32768 / nc;
    for (int c = 0; c < nc; c++) {
      int tok_base = c * chunk + 128;
      gemm_bf16<<<dim3(12, chunk / 128), 256, 0, stream>>>(
          x, 512, tok_base, SEQ_MASK, 1, Wt, bqkv, 1, qkvb, 1536, 0,
          0, 0x7fffffff, 512, flag);
      rope_rms_k<<<chunk * 2, 256, 0, stream>>>(qkvb, coords, gq, gk, tok_base, flag);
      attn_mfma_k<<<(chunk / 256) * 8, 256, 0, stream>>>(qkvb);
      gemm_bf16<<<dim3(4, chunk / 128), 256, 0, stream>>>(
          qkvb, 1536, 0, 0x7fffffff, 0, Wot, bout, 1, d_out, 512, 1,
          tok_base, SEQ_MASK, 512, flag);
    }
  }
}